// Round 5
// baseline (46.151 us; speedup 1.0000x reference)
//
#include <hip/hip_runtime.h>
#include <math.h>

// Problem constants (fixed by setup_inputs)
constexpr int kB = 32;         // batch
constexpr int kS = 128;        // seq len
constexpr int kD = 256;        // hidden
constexpr int kK = 8;          // window
constexpr int kNPair = 2104;   // pairs with |j-i|<=8
constexpr int kInDim = 576;    // 2D + P
constexpr int kRS = 264;       // padded f32 LDS row stride

typedef __attribute__((ext_vector_type(8))) short short8;   // 8 bf16
typedef __attribute__((ext_vector_type(4))) float f32x4;    // MFMA C/D frag
typedef unsigned int u32;

// f32 -> bf16, round-to-nearest-even
__device__ inline ushort f2b(float f) {
  union { float f; uint u; } v; v.f = f;
  uint r = v.u + 0x7FFF + ((v.u >> 16) & 1);
  return (ushort)(r >> 16);
}

// async global->LDS DMA: 16 B per lane; lds base must be wave-uniform
__device__ inline void gload16(const void* g, void* lds) {
  __builtin_amdgcn_global_load_lds(
      (const u32 __attribute__((address_space(1)))*)g,
      (u32 __attribute__((address_space(3)))*)lds, 16, 0, 0);
}

// ---------------------------------------------------------------------------
// prep: one-time conversions into workspace.
//  blocks 0..255 : Hb[4096][256] bf16, per-row XOR-swizzled LDS image
//  blocks 256..287: Wb[8][64][256] bf16 tile images (tile nt = output cols nt*64..)
//  block 288      : Rg[17][256] f32 = Kpe @ W1c^T + b1
// ---------------------------------------------------------------------------
__global__ __launch_bounds__(256) void prep(
    const float* __restrict__ H, const float* __restrict__ pos_emb,
    const float* __restrict__ W1, const float* __restrict__ b1,
    ushort* __restrict__ Hb, ushort* __restrict__ Wb, float* __restrict__ Rg) {
  const int blk = blockIdx.x, tid = threadIdx.x;
  if (blk < 256) {
#pragma unroll
    for (int l = 0; l < 4; ++l) {
      int c = blk * 1024 + l * 256 + tid;      // [0, 262144)
      int row = c >> 6, kq = (c & 63) << 2;
      float4 a = *(const float4*)(H + row * kD + kq);
      ushort4 u; u.x = f2b(a.x); u.y = f2b(a.y); u.z = f2b(a.z); u.w = f2b(a.w);
      *(ushort4*)(Hb + row * 256 + (kq ^ ((row & 7) << 3))) = u;
    }
  } else if (blk < 288) {
    int bb = blk - 256;
#pragma unroll
    for (int l = 0; l < 4; ++l) {
      int c = bb * 1024 + l * 256 + tid;       // [0, 32768)
      int r = c >> 6;                          // output col 0..511
      int kq = (c & 63) << 2;
      int nt = r >> 6, rr = r & 63;
      const float* src = W1 + (r & 255) * kInDim + ((r < 256) ? 0 : 256) + kq;
      float4 a = *(const float4*)src;
      ushort4 u; u.x = f2b(a.x); u.y = f2b(a.y); u.z = f2b(a.z); u.w = f2b(a.w);
      *(ushort4*)(Wb + (nt * 64 + rr) * 256 + (kq ^ ((rr & 7) << 3))) = u;
    }
  } else {
    // R[t][d] = sum_u (128-|u-8|)*exp(-(t-u)^2)*(pos_emb[u].W1c[d]) + b1[d]
    __shared__ float pe[17 * 64];
    for (int idx = tid; idx < 17 * 64; idx += 256) pe[idx] = pos_emb[idx];
    __syncthreads();
    const int d = tid;
    float w[64];
    const float* wr = W1 + d * kInDim + 512;
#pragma unroll
    for (int q = 0; q < 16; ++q) {
      float4 t4 = *(const float4*)(wr + q * 4);
      w[q * 4 + 0] = t4.x; w[q * 4 + 1] = t4.y;
      w[q * 4 + 2] = t4.z; w[q * 4 + 3] = t4.w;
    }
    float acc[17];
#pragma unroll
    for (int t = 0; t < 17; ++t) acc[t] = 0.f;
    for (int u = 0; u < 17; ++u) {
      float m = 0.f;
#pragma unroll
      for (int p = 0; p < 64; ++p) m += pe[u * 64 + p] * w[p];
      int au = u - kK; if (au < 0) au = -au;
      m *= (float)(kS - au);
#pragma unroll
      for (int t = 0; t < 17; ++t) {
        int dd = t - u;
        acc[t] += expf((float)(-(dd * dd))) * m;
      }
    }
#pragma unroll
    for (int t = 0; t < 17; ++t) Rg[t * kD + d] = acc[t] + b1[d];
  }
}

// ---------------------------------------------------------------------------
// fused2: block = (batch b, 16-row i-chunk), 512 threads = 8 waves.
//  stage sH + sW(t0) via global_load_lds -> 8x { MFMA U/V ; prefetch-issue
//  next W tile ; write accs } -> pair phase from LDS (U row in registers).
// ---------------------------------------------------------------------------
__global__ __launch_bounds__(512, 2) void fused2(
    const ushort* __restrict__ Hb, const ushort* __restrict__ Wb,
    const float* __restrict__ Rg,
    const float* __restrict__ ln_g, const float* __restrict__ ln_b,
    const float* __restrict__ W2, const float* __restrict__ b2,
    float* __restrict__ out) {
  __shared__ __align__(16) ushort sH[48 * 256];   // 24 KB (pre-swizzled image)
  __shared__ __align__(16) ushort sW[64 * 256];   // 32 KB (pre-swizzled image)
  __shared__ float sU[16 * kRS];                  // ~17 KB
  __shared__ float sV[48 * kRS];                  // ~51 KB
  __shared__ float sR[17 * kRS];                  // ~18 KB
  __shared__ float sG[256], sBe[256], sWo[256];

  const int tid = threadIdx.x;
  const int lane = tid & 63;
  const int b = blockIdx.x >> 3;
  const int i0 = (blockIdx.x & 7) << 4;
  int ws_ = i0 - 16; if (ws_ < 0) ws_ = 0; if (ws_ > 80) ws_ = 80;
  const int ws = ws_;                             // window start (mult of 16)
  const int oi = i0 - ws;

  // ---- stage: sH (1536x16B) + sW tile0 (2048x16B) via DMA; params/R plain ----
  {
    const ushort* src = Hb + (b * kS + ws) * 256; // contiguous 24 KB
    for (int idx = tid; idx < 1536; idx += 512)
      gload16(src + idx * 8, (char*)sH + (idx - lane) * 16);
  }
  for (int idx = tid; idx < 2048; idx += 512)
    gload16(Wb + idx * 8, (char*)sW + (idx - lane) * 16);
  if (tid < 256) { sG[tid] = ln_g[tid]; sBe[tid] = ln_b[tid]; sWo[tid] = W2[tid]; }
  for (int idx = tid; idx < 1088; idx += 512) {
    float4 a = *(const float4*)(Rg + idx * 4);
    int t = idx >> 6, d = (idx & 63) << 2;
    *(float4*)&sR[t * kRS + d] = a;
  }
  __syncthreads();   // drains vmcnt -> sH, sW(t0) ready

  const int w = tid >> 6;
  const int lr = lane & 15;
  const int lk = (lane >> 4) << 3;
  const int swz = (lr & 7) << 3;
  const int r0 = (lane >> 4) << 2;

  // ---- phase 2: 8 n-tiles; MFMA by waves 0-3; writes overlap next DMA ----
  for (int nt = 0; nt < 8; ++nt) {
    f32x4 acc[3] = {{0,0,0,0},{0,0,0,0},{0,0,0,0}};
    if (w < 4) {
      const int brow = (w << 4) + lr;
#pragma unroll
      for (int kk = 0; kk < 8; ++kk) {
        int k0 = (kk << 5) + lk;
        short8 bf = *(const short8*)(const void*)&sW[brow * 256 + (k0 ^ swz)];
#pragma unroll
        for (int m = 0; m < 3; ++m) {
          short8 af = *(const short8*)(const void*)&sH[(m * 16 + lr) * 256 + (k0 ^ swz)];
          acc[m] = __builtin_amdgcn_mfma_f32_16x16x32_bf16(af, bf, acc[m], 0, 0, 0);
        }
      }
    }
    __syncthreads();                 // all done reading sW
    if (nt < 7) {                    // issue next tile DMA (completes at next barrier)
      const ushort* src = Wb + (nt + 1) * 16384;
      for (int idx = tid; idx < 2048; idx += 512)
        gload16(src + idx * 8, (char*)sW + (idx - lane) * 16);
    }
    if (w < 4) {                     // write accs while DMA is in flight
      const int cg = (nt << 6) + (w << 4) + lr;
#pragma unroll
      for (int m = 0; m < 3; ++m)
#pragma unroll
        for (int r = 0; r < 4; ++r) {
          int rw = m * 16 + r0 + r;
          float val = acc[m][r];
          if (cg < 256) { unsigned ur = (unsigned)(rw - oi); if (ur < 16u) sU[ur * kRS + cg] = val; }
          else sV[rw * kRS + (cg - 256)] = val;
        }
    }
    __syncthreads();                 // sW(nt+1) ready; sU/sV visible
  }

  // ---- phase 3: 32 groups = 16 i-rows x 2 t-halves; U row in registers ----
  const int g = tid >> 4, l16 = tid & 15;
  const int ir = g >> 1;
  const int tbeg = (g & 1) ? 9 : 0;
  const int tend = (g & 1) ? 17 : 9;
  const int i = i0 + ir;

  float ureg[16];
#pragma unroll
  for (int q = 0; q < 4; ++q) {
    float4 u4 = *(const float4*)&sU[ir * kRS + (q << 6) + (l16 << 2)];
    ureg[q * 4 + 0] = u4.x; ureg[q * 4 + 1] = u4.y;
    ureg[q * 4 + 2] = u4.z; ureg[q * 4 + 3] = u4.w;
  }
  float4 Gp[4], Bp[4], Wp[4];
#pragma unroll
  for (int q = 0; q < 4; ++q) {
    int d = (q << 6) + (l16 << 2);
    Gp[q] = *(const float4*)&sG[d];
    Bp[q] = *(const float4*)&sBe[d];
    Wp[q] = *(const float4*)&sWo[d];
  }
  const float bias2 = b2[0];

  int start_i;
  if (i <= 8)        start_i = (i * i + 17 * i) / 2;
  else if (i <= 120) start_i = 100 + (i - 8) * 17;
  else { int m = i - 120; start_i = 2004 + 16 * m - (m * (m - 1)) / 2; }
  const int lower = (i - kK > 0) ? (i - kK) : 0;

  for (int t = tbeg; t < tend; ++t) {
    int j = i - kK + t;
    if (j < 0 || j >= kS) continue;            // group-uniform
    const int vr = j - ws;
    const int p = start_i + (j - lower);
    const float* Vr = &sV[vr * kRS];
    const float* Rr = &sR[t * kRS];

    float h[16]; float ssum = 0.f, qsum = 0.f;
#pragma unroll
    for (int q = 0; q < 4; ++q) {
      int d = (q << 6) + (l16 << 2);
      float4 v4 = *(const float4*)(Vr + d);
      float4 r4 = *(const float4*)(Rr + d);
      float h0 = ureg[q * 4 + 0] + v4.x + r4.x;
      float h1 = ureg[q * 4 + 1] + v4.y + r4.y;
      float h2 = ureg[q * 4 + 2] + v4.z + r4.z;
      float h3 = ureg[q * 4 + 3] + v4.w + r4.w;
      h[q * 4 + 0] = h0; h[q * 4 + 1] = h1; h[q * 4 + 2] = h2; h[q * 4 + 3] = h3;
      ssum += h0 + h1 + h2 + h3;
      qsum += h0 * h0 + h1 * h1 + h2 * h2 + h3 * h3;
    }
#pragma unroll
    for (int off = 8; off > 0; off >>= 1) {
      ssum += __shfl_xor(ssum, off);
      qsum += __shfl_xor(qsum, off);
    }
    const float mu = ssum * (1.0f / kD);
    const float var = qsum * (1.0f / kD) - mu * mu;
    const float rs = rsqrtf(var + 1e-5f);
    float dot = 0.f;
#pragma unroll
    for (int q = 0; q < 4; ++q) {
      float y0 = (h[q * 4 + 0] - mu) * rs * Gp[q].x + Bp[q].x;
      float y1 = (h[q * 4 + 1] - mu) * rs * Gp[q].y + Bp[q].y;
      float y2 = (h[q * 4 + 2] - mu) * rs * Gp[q].z + Bp[q].z;
      float y3 = (h[q * 4 + 3] - mu) * rs * Gp[q].w + Bp[q].w;
      y0 = y0 > 0.f ? y0 : (__expf(y0) - 1.0f);
      y1 = y1 > 0.f ? y1 : (__expf(y1) - 1.0f);
      y2 = y2 > 0.f ? y2 : (__expf(y2) - 1.0f);
      y3 = y3 > 0.f ? y3 : (__expf(y3) - 1.0f);
      dot += y0 * Wp[q].x + y1 * Wp[q].y + y2 * Wp[q].z + y3 * Wp[q].w;
    }
#pragma unroll
    for (int off = 8; off > 0; off >>= 1) dot += __shfl_xor(dot, off);

    if (l16 == 0) {
      out[b * kNPair + p] = dot + bias2;
      if (b == 0) {
        float* po = out + kB * kNPair;         // positions read back as f32
        po[2 * p + 0] = (float)(i + 1);
        po[2 * p + 1] = (float)(j + 1);
      }
    }
  }
}

// ---------------------------------------------------------------------------
extern "C" void kernel_launch(void* const* d_in, const int* in_sizes, int n_in,
                              void* d_out, int out_size, void* d_ws, size_t ws_size,
                              hipStream_t stream) {
  (void)in_sizes; (void)n_in; (void)ws_size; (void)out_size;
  const float* H       = (const float*)d_in[0];  // [32,128,256]
  const float* pos_emb = (const float*)d_in[1];  // [17,64]
  const float* W1      = (const float*)d_in[2];  // [256,576]
  const float* b1      = (const float*)d_in[3];  // [256]
  const float* ln_g    = (const float*)d_in[4];  // [256]
  const float* ln_b    = (const float*)d_in[5];  // [256]
  const float* W2      = (const float*)d_in[6];  // [1,256]
  const float* b2      = (const float*)d_in[7];  // [1]
  float* out = (float*)d_out;

  ushort* Hb = (ushort*)d_ws;                 // [4096][256] bf16 swizzled
  ushort* Wb = Hb + 4096 * 256;               // [8][64][256] bf16 tile images
  float*  Rg = (float*)(Wb + 512 * 256);      // [17][256] f32

  prep<<<289, 256, 0, stream>>>(H, pos_emb, W1, b1, Hb, Wb, Rg);
  fused2<<<kB * 8, 512, 0, stream>>>(Hb, Wb, Rg, ln_g, ln_b, W2, b2, out);
}